// Round 3
// baseline (223.181 us; speedup 1.0000x reference)
//
#include <hip/hip_runtime.h>
#include <hip/hip_bf16.h>

#define BB 2
#define SS 2048
#define EE 1024
#define HH 16
#define DD 64
#define MT (BB*SS)     // 4096 tokens
#define NQ (3*EE)      // 3072

typedef unsigned short u16;
typedef __bf16 bf16t;
typedef bf16t bf16x8 __attribute__((ext_vector_type(8)));
typedef short short8v __attribute__((ext_vector_type(8)));
typedef float f32x4 __attribute__((ext_vector_type(4)));

#define AS1 __attribute__((address_space(1)))
#define AS3 __attribute__((address_space(3)))

__device__ __forceinline__ u16 f2b(float f) {
  unsigned u = __builtin_bit_cast(unsigned, f);
  u += 0x7FFF + ((u >> 16) & 1);   // RNE
  return (u16)(u >> 16);
}

__device__ __forceinline__ void gload_lds16(const void* g, void* l) {
  __builtin_amdgcn_global_load_lds((const AS1 void*)(g), (AS3 void*)(l), 16, 0, 0);
}

__device__ __forceinline__ f32x4 mfma_bf16(short8v a, short8v b, f32x4 c) {
  return __builtin_amdgcn_mfma_f32_16x16x32_bf16(
      __builtin_bit_cast(bf16x8, a), __builtin_bit_cast(bf16x8, b), c, 0, 0, 0);
}

// scale folded into Q: 1/sqrt(64) * log2(e)
#define QSCALE 0.18033688f

// ---------------- prologue: cast x -> bf16 ----------------
__global__ void __launch_bounds__(256) cast_kernel(const float* __restrict__ in,
                                                   u16* __restrict__ out, int n) {
  int i = (blockIdx.x * 256 + threadIdx.x) * 4;
  if (i + 3 < n) {
    float4 v = *(const float4*)(in + i);
    ushort4 o;
    o.x = f2b(v.x); o.y = f2b(v.y); o.z = f2b(v.z); o.w = f2b(v.w);
    *(ushort4*)(out + i) = o;
  }
}

// W [K][N] f32 -> WT [N][K] bf16, 64x64 LDS tile (coalesced both sides)
__global__ void __launch_bounds__(256) transpose_kernel(const float* __restrict__ W,
                                                        u16* __restrict__ WT,
                                                        int K, int N) {
  __shared__ float t[64][65];
  int k0 = blockIdx.y * 64, n0 = blockIdx.x * 64;
  int r = threadIdx.x >> 4;          // 0..15
  int c4 = (threadIdx.x & 15) * 4;   // 0..60
#pragma unroll
  for (int i = 0; i < 4; ++i) {
    float4 v = *(const float4*)(W + (size_t)(k0 + r + i * 16) * N + n0 + c4);
    t[r + i * 16][c4 + 0] = v.x; t[r + i * 16][c4 + 1] = v.y;
    t[r + i * 16][c4 + 2] = v.z; t[r + i * 16][c4 + 3] = v.w;
  }
  __syncthreads();
#pragma unroll
  for (int i = 0; i < 4; ++i) {
    ushort4 o;
    o.x = f2b(t[c4 + 0][r + i * 16]); o.y = f2b(t[c4 + 1][r + i * 16]);
    o.z = f2b(t[c4 + 2][r + i * 16]); o.w = f2b(t[c4 + 3][r + i * 16]);
    *(ushort4*)(WT + (size_t)(n0 + r + i * 16) * K + k0 + c4) = o;
  }
}

// ---------------- QKV GEMM: C[4096,3072] = x @ Wqkv + b, scatter to Q,K,Vt ----------------
__global__ void __launch_bounds__(256) gemm_qkv_kernel(
    const u16* __restrict__ A, const u16* __restrict__ BT,
    const float* __restrict__ bias,
    u16* __restrict__ Qs, u16* __restrict__ Ks, u16* __restrict__ Vt) {
  __shared__ u16 As[4096];
  __shared__ u16 Bs[4096];
  const int K = EE;
  int tid = threadIdx.x;
  int w = tid >> 6, lane = tid & 63;
  int g = lane >> 4, q = lane & 15;
  int m0 = blockIdx.y * 128, n0 = blockIdx.x * 128;
  int wm = (w >> 1) * 64, wn = (w & 1) * 64;

  f32x4 acc[4][4] = {};

  int r = tid >> 2;
  int kc = (tid & 3) * 8;
  const u16* ga = A + (size_t)(m0 + r) * K + kc;
  const u16* gb = BT + (size_t)(n0 + r) * K + kc;
  u16* lA0 = As + w * 512;
  u16* lA1 = As + 2048 + w * 512;
  u16* lB0 = Bs + w * 512;
  u16* lB1 = Bs + 2048 + w * 512;

  for (int k0 = 0; k0 < K; k0 += 32) {
    gload_lds16(ga, lA0);
    gload_lds16(ga + 64 * K, lA1);
    gload_lds16(gb, lB0);
    gload_lds16(gb + 64 * K, lB1);
    ga += 32; gb += 32;
    __syncthreads();
    short8v af[4], bfv[4];
#pragma unroll
    for (int m = 0; m < 4; ++m)
      af[m] = *(const short8v*)(As + (wm + m * 16 + q) * 32 + g * 8);
#pragma unroll
    for (int n = 0; n < 4; ++n)
      bfv[n] = *(const short8v*)(Bs + (wn + n * 16 + q) * 32 + g * 8);
#pragma unroll
    for (int m = 0; m < 4; ++m)
#pragma unroll
      for (int n = 0; n < 4; ++n)
        acc[m][n] = mfma_bf16(af[m], bfv[n], acc[m][n]);
    __syncthreads();
  }

#pragma unroll
  for (int m = 0; m < 4; ++m) {
    int row0 = m0 + wm + m * 16 + g * 4;
#pragma unroll
    for (int n = 0; n < 4; ++n) {
      int col = n0 + wn + n * 16 + q;
      float bi = bias[col];
      int t = col >> 10;
      int h = (col >> 6) & 15;
      int d = col & 63;
#pragma unroll
      for (int r2 = 0; r2 < 4; ++r2) {
        int row = row0 + r2;
        int b = row >> 11, s = row & 2047;
        float v = acc[m][n][r2] + bi;
        size_t bh = (size_t)b * HH + h;
        if (t == 0)      Qs[(bh * SS + s) * DD + d] = f2b(v * QSCALE);
        else if (t == 1) Ks[(bh * SS + s) * DD + d] = f2b(v);
        else             Vt[(bh * DD + d) * SS + s] = f2b(v);
      }
    }
  }
}

// ---------------- causal flash attention ----------------
// Barrier-free: 4 independent waves/block, each owns 32 q-rows; K/V read
// directly from global (L2-resident per XCD via bh->XCD placement).
// qt pairing (2p,2p+1,63-2p,62-2p) makes every block exactly 66 tile-passes.
__global__ void __launch_bounds__(256) attn_kernel(
    const u16* __restrict__ Qg, const u16* __restrict__ Kg,
    const u16* __restrict__ Vg, u16* __restrict__ O) {
  __shared__ char lds[16384];          // per-wave 4KB P buffer (32x64 bf16, swizzled)
  int tid = threadIdx.x;
  int w = tid >> 6, lane = tid & 63;
  int g = lane >> 4, q = lane & 15;
  int sid = blockIdx.x;
  int xcd = sid & 7, idx = sid >> 3;
  int bh = xcd + 8 * (idx & 3);        // 4 heads per XCD -> K/V L2-resident
  int p = idx >> 2;                    // 0..15
  int pb = 2 * p + (w & 1);
  int qt = (w < 2) ? pb : 63 - pb;     // balanced pairing
  int qw = qt * 32;
  char* Pw = lds + w * 4096;

  const char* Qp = (const char*)Qg + (size_t)bh * (SS * 128);
  const char* Kp = (const char*)Kg + (size_t)bh * (SS * 128);
  const char* Vp = (const char*)Vg + (size_t)bh * (SS * 128);  // [d][s]

  short8v aq[2][2];
#pragma unroll
  for (int m = 0; m < 2; ++m)
#pragma unroll
    for (int j = 0; j < 2; ++j)
      aq[m][j] = *(const short8v*)(Qp + (size_t)(qw + m * 16 + q) * 128 + j * 64 + g * 16);

  f32x4 oacc[2][4] = {};
  float mrun[2][4], lrun[2][4];
#pragma unroll
  for (int m = 0; m < 2; ++m)
#pragma unroll
    for (int r2 = 0; r2 < 4; ++r2) { mrun[m][r2] = -1e30f; lrun[m][r2] = 0.f; }

  const int nt = (qw >> 6) + 1;
  for (int t = 0; t < nt; ++t) {
    int kv0 = t << 6;
    // ---- K fragments (direct global, L2-hot) ----
    short8v kf[4][2];
#pragma unroll
    for (int c = 0; c < 4; ++c) {
      const char* kp = Kp + (size_t)(kv0 + c * 16 + q) * 128 + g * 16;
      kf[c][0] = *(const short8v*)kp;
      kf[c][1] = *(const short8v*)(kp + 64);
    }
    // ---- QK^T (Q pre-scaled by 1/8*log2e) ----
    f32x4 st[2][4];
#pragma unroll
    for (int m = 0; m < 2; ++m)
#pragma unroll
      for (int c = 0; c < 4; ++c) {
        f32x4 z = {};
        z = mfma_bf16(aq[m][0], kf[c][0], z);
        z = mfma_bf16(aq[m][1], kf[c][1], z);
        st[m][c] = z;
      }
    // ---- V fragments: issue before softmax so L2 latency hides under VALU ----
    short8v vf[4][2];
#pragma unroll
    for (int v = 0; v < 4; ++v) {
      const char* vp = Vp + (size_t)(v * 16 + q) * (SS * 2) + (size_t)kv0 * 2 + g * 16;
      vf[v][0] = *(const short8v*)vp;
      vf[v][1] = *(const short8v*)(vp + 64);
    }
    // ---- causal mask (diagonal tiles only) ----
    if (kv0 + 63 > qw) {
#pragma unroll
      for (int m = 0; m < 2; ++m)
#pragma unroll
        for (int c = 0; c < 4; ++c) {
          int col = kv0 + c * 16 + q;
#pragma unroll
          for (int r2 = 0; r2 < 4; ++r2) {
            int row = qw + m * 16 + g * 4 + r2;
            if (col > row) st[m][c][r2] = -1e30f;
          }
        }
    }
    // ---- online softmax (base-2 domain) ----
#pragma unroll
    for (int m = 0; m < 2; ++m)
#pragma unroll
      for (int r2 = 0; r2 < 4; ++r2) {
        float mx = fmaxf(fmaxf(st[m][0][r2], st[m][1][r2]),
                         fmaxf(st[m][2][r2], st[m][3][r2]));
        mx = fmaxf(mx, __shfl_xor(mx, 1));
        mx = fmaxf(mx, __shfl_xor(mx, 2));
        mx = fmaxf(mx, __shfl_xor(mx, 4));
        mx = fmaxf(mx, __shfl_xor(mx, 8));
        float mnew = fmaxf(mrun[m][r2], mx);
        float alpha = exp2f(mrun[m][r2] - mnew);
        mrun[m][r2] = mnew;
        float s = 0.f;
#pragma unroll
        for (int c = 0; c < 4; ++c) {
          float pv = exp2f(st[m][c][r2] - mnew);
          st[m][c][r2] = pv;
          s += pv;
        }
        s += __shfl_xor(s, 1); s += __shfl_xor(s, 2);
        s += __shfl_xor(s, 4); s += __shfl_xor(s, 8);
        lrun[m][r2] = lrun[m][r2] * alpha + s;
#pragma unroll
        for (int vfi = 0; vfi < 4; ++vfi) oacc[m][vfi][r2] *= alpha;
      }
    // ---- P -> per-wave LDS (swizzled) ----
#pragma unroll
    for (int m = 0; m < 2; ++m)
#pragma unroll
      for (int c = 0; c < 4; ++c) {
        int colb = (c * 16 + q) * 2;
#pragma unroll
        for (int r2 = 0; r2 < 4; ++r2) {
          int row = m * 16 + g * 4 + r2;
          *(u16*)(Pw + row * 128 + (colb ^ ((row & 7) << 4))) = f2b(st[m][c][r2]);
        }
      }
    short8v pa[2][2];
#pragma unroll
    for (int m = 0; m < 2; ++m) {
      int row = m * 16 + q;
#pragma unroll
      for (int j = 0; j < 2; ++j)
        pa[m][j] = *(const short8v*)(Pw + row * 128 + ((j * 64 + g * 16) ^ ((row & 7) << 4)));
    }
    // ---- PV ----
#pragma unroll
    for (int m = 0; m < 2; ++m)
#pragma unroll
      for (int vfi = 0; vfi < 4; ++vfi) {
        oacc[m][vfi] = mfma_bf16(pa[m][0], vf[vfi][0], oacc[m][vfi]);
        oacc[m][vfi] = mfma_bf16(pa[m][1], vf[vfi][1], oacc[m][vfi]);
      }
  }

  int b = bh >> 4, h = bh & 15;
#pragma unroll
  for (int m = 0; m < 2; ++m)
#pragma unroll
    for (int r2 = 0; r2 < 4; ++r2) {
      float inv = 1.0f / lrun[m][r2];
      int row = qw + m * 16 + g * 4 + r2;
      u16* base = O + ((size_t)b * SS + row) * EE + h * 64;
#pragma unroll
      for (int vfi = 0; vfi < 4; ++vfi)
        base[vfi * 16 + q] = f2b(oacc[m][vfi][r2] * inv);
    }
}

// ---------------- output projection GEMM: out[4096,1024] = O @ Wout + bout (f32) ----------------
__global__ void __launch_bounds__(256) gemm_out_kernel(
    const u16* __restrict__ A, const u16* __restrict__ BT,
    const float* __restrict__ bias, float* __restrict__ Cout) {
  __shared__ u16 As[4096];
  __shared__ u16 Bs[4096];
  const int K = EE;
  int tid = threadIdx.x;
  int w = tid >> 6, lane = tid & 63;
  int g = lane >> 4, q = lane & 15;
  int m0 = blockIdx.y * 128, n0 = blockIdx.x * 128;
  int wm = (w >> 1) * 64, wn = (w & 1) * 64;

  f32x4 acc[4][4] = {};

  int r = tid >> 2;
  int kc = (tid & 3) * 8;
  const u16* ga = A + (size_t)(m0 + r) * K + kc;
  const u16* gb = BT + (size_t)(n0 + r) * K + kc;
  u16* lA0 = As + w * 512;
  u16* lA1 = As + 2048 + w * 512;
  u16* lB0 = Bs + w * 512;
  u16* lB1 = Bs + 2048 + w * 512;

  for (int k0 = 0; k0 < K; k0 += 32) {
    gload_lds16(ga, lA0);
    gload_lds16(ga + 64 * K, lA1);
    gload_lds16(gb, lB0);
    gload_lds16(gb + 64 * K, lB1);
    ga += 32; gb += 32;
    __syncthreads();
    short8v af[4], bfv[4];
#pragma unroll
    for (int m = 0; m < 4; ++m)
      af[m] = *(const short8v*)(As + (wm + m * 16 + q) * 32 + g * 8);
#pragma unroll
    for (int n = 0; n < 4; ++n)
      bfv[n] = *(const short8v*)(Bs + (wn + n * 16 + q) * 32 + g * 8);
#pragma unroll
    for (int m = 0; m < 4; ++m)
#pragma unroll
      for (int n = 0; n < 4; ++n)
        acc[m][n] = mfma_bf16(af[m], bfv[n], acc[m][n]);
    __syncthreads();
  }

#pragma unroll
  for (int m = 0; m < 4; ++m) {
    int row0 = m0 + wm + m * 16 + g * 4;
#pragma unroll
    for (int n = 0; n < 4; ++n) {
      int col = n0 + wn + n * 16 + q;
      float bi = bias[col];
#pragma unroll
      for (int r2 = 0; r2 < 4; ++r2) {
        int row = row0 + r2;
        Cout[(size_t)row * EE + col] = acc[m][n][r2] + bi;
      }
    }
  }
}

extern "C" void kernel_launch(void* const* d_in, const int* in_sizes, int n_in,
                              void* d_out, int out_size, void* d_ws, size_t ws_size,
                              hipStream_t stream) {
  (void)in_sizes; (void)n_in; (void)out_size; (void)ws_size;
  const float* x    = (const float*)d_in[0];
  const float* Wqkv = (const float*)d_in[1];
  const float* bqkv = (const float*)d_in[2];
  const float* Wout = (const float*)d_in[3];
  const float* bout = (const float*)d_in[4];
  float* out = (float*)d_out;

  char* p = (char*)d_ws;
  u16* xb  = (u16*)p; p += (size_t)MT * EE * 2;           // 8 MB
  u16* wqT = (u16*)p; p += (size_t)NQ * EE * 2;           // 6 MB
  u16* woT = (u16*)p; p += (size_t)EE * EE * 2;           // 2 MB
  u16* Qs  = (u16*)p; p += (size_t)BB * HH * SS * DD * 2; // 8 MB
  u16* Ks  = (u16*)p; p += (size_t)BB * HH * SS * DD * 2; // 8 MB
  u16* Vt  = (u16*)p; p += (size_t)BB * HH * DD * SS * 2; // 8 MB
  u16* Ob  = (u16*)p; p += (size_t)MT * EE * 2;           // 8 MB

  cast_kernel<<<dim3((MT * EE / 4) / 256), dim3(256), 0, stream>>>(x, xb, MT * EE);
  transpose_kernel<<<dim3(NQ / 64, EE / 64), dim3(256), 0, stream>>>(Wqkv, wqT, EE, NQ);
  transpose_kernel<<<dim3(EE / 64, EE / 64), dim3(256), 0, stream>>>(Wout, woT, EE, EE);
  gemm_qkv_kernel<<<dim3(NQ / 128, MT / 128), dim3(256), 0, stream>>>(xb, wqT, bqkv, Qs, Ks, Vt);
  attn_kernel<<<dim3(512), dim3(256), 0, stream>>>(Qs, Ks, Vt, Ob);
  gemm_out_kernel<<<dim3(EE / 128, MT / 128), dim3(256), 0, stream>>>(Ob, woT, bout, out);
}

// Round 5
// 146.747 us; speedup vs baseline: 1.5209x; 1.5209x over previous
//
#include <hip/hip_runtime.h>
#include <hip/hip_bf16.h>

#define BB 2
#define SS 2048
#define EE 1024
#define HH 16
#define DD 64
#define MT (BB*SS)     // 4096 tokens
#define NQ (3*EE)      // 3072

typedef unsigned short u16;
typedef __bf16 bf16t;
typedef bf16t bf16x8 __attribute__((ext_vector_type(8)));
typedef short short8v __attribute__((ext_vector_type(8)));
typedef float f32x4 __attribute__((ext_vector_type(4)));

#define AS1 __attribute__((address_space(1)))
#define AS3 __attribute__((address_space(3)))

__device__ __forceinline__ u16 f2b(float f) {
  unsigned u = __builtin_bit_cast(unsigned, f);
  u += 0x7FFF + ((u >> 16) & 1);   // RNE
  return (u16)(u >> 16);
}

__device__ __forceinline__ unsigned cvtpk(float lo, float hi) {
  unsigned r;
  asm("v_cvt_pk_bf16_f32 %0, %1, %2" : "=v"(r) : "v"(lo), "v"(hi));
  return r;
}

__device__ __forceinline__ void gload_lds16(const void* g, void* l) {
  __builtin_amdgcn_global_load_lds((const AS1 void*)(g), (AS3 void*)(l), 16, 0, 0);
}

__device__ __forceinline__ f32x4 mfma_bf16(short8v a, short8v b, f32x4 c) {
  return __builtin_amdgcn_mfma_f32_16x16x32_bf16(
      __builtin_bit_cast(bf16x8, a), __builtin_bit_cast(bf16x8, b), c, 0, 0, 0);
}

// scale folded into Q: 1/sqrt(64) * log2(e)
#define QSCALE 0.18033688f

// ---------------- prologue: cast x -> bf16 ----------------
__global__ void __launch_bounds__(256) cast_kernel(const float* __restrict__ in,
                                                   u16* __restrict__ out, int n) {
  int i = (blockIdx.x * 256 + threadIdx.x) * 4;
  if (i + 3 < n) {
    float4 v = *(const float4*)(in + i);
    ushort4 o;
    o.x = f2b(v.x); o.y = f2b(v.y); o.z = f2b(v.z); o.w = f2b(v.w);
    *(ushort4*)(out + i) = o;
  }
}

// W [K][N] f32 -> WT [N][K] bf16, 64x64 LDS tile (coalesced both sides)
__global__ void __launch_bounds__(256) transpose_kernel(const float* __restrict__ W,
                                                        u16* __restrict__ WT,
                                                        int K, int N) {
  __shared__ float t[64][65];
  int k0 = blockIdx.y * 64, n0 = blockIdx.x * 64;
  int r = threadIdx.x >> 4;          // 0..15
  int c4 = (threadIdx.x & 15) * 4;   // 0..60
#pragma unroll
  for (int i = 0; i < 4; ++i) {
    float4 v = *(const float4*)(W + (size_t)(k0 + r + i * 16) * N + n0 + c4);
    t[r + i * 16][c4 + 0] = v.x; t[r + i * 16][c4 + 1] = v.y;
    t[r + i * 16][c4 + 2] = v.z; t[r + i * 16][c4 + 3] = v.w;
  }
  __syncthreads();
#pragma unroll
  for (int i = 0; i < 4; ++i) {
    ushort4 o;
    o.x = f2b(t[c4 + 0][r + i * 16]); o.y = f2b(t[c4 + 1][r + i * 16]);
    o.z = f2b(t[c4 + 2][r + i * 16]); o.w = f2b(t[c4 + 3][r + i * 16]);
    *(ushort4*)(WT + (size_t)(n0 + r + i * 16) * K + k0 + c4) = o;
  }
}

// ---------------- QKV GEMM: C[4096,3072] = x @ Wqkv + b, scatter to Q,K,Vt ----------------
__global__ void __launch_bounds__(256) gemm_qkv_kernel(
    const u16* __restrict__ A, const u16* __restrict__ BT,
    const float* __restrict__ bias,
    u16* __restrict__ Qs, u16* __restrict__ Ks, u16* __restrict__ Vt) {
  __shared__ u16 As[4096];
  __shared__ u16 Bs[4096];
  const int K = EE;
  int tid = threadIdx.x;
  int w = tid >> 6, lane = tid & 63;
  int g = lane >> 4, q = lane & 15;
  int m0 = blockIdx.y * 128, n0 = blockIdx.x * 128;
  int wm = (w >> 1) * 64, wn = (w & 1) * 64;

  f32x4 acc[4][4] = {};

  int r = tid >> 2;
  int kc = (tid & 3) * 8;
  const u16* ga = A + (size_t)(m0 + r) * K + kc;
  const u16* gb = BT + (size_t)(n0 + r) * K + kc;
  u16* lA0 = As + w * 512;
  u16* lA1 = As + 2048 + w * 512;
  u16* lB0 = Bs + w * 512;
  u16* lB1 = Bs + 2048 + w * 512;

  for (int k0 = 0; k0 < K; k0 += 32) {
    gload_lds16(ga, lA0);
    gload_lds16(ga + 64 * K, lA1);
    gload_lds16(gb, lB0);
    gload_lds16(gb + 64 * K, lB1);
    ga += 32; gb += 32;
    __syncthreads();
    short8v af[4], bfv[4];
#pragma unroll
    for (int m = 0; m < 4; ++m)
      af[m] = *(const short8v*)(As + (wm + m * 16 + q) * 32 + g * 8);
#pragma unroll
    for (int n = 0; n < 4; ++n)
      bfv[n] = *(const short8v*)(Bs + (wn + n * 16 + q) * 32 + g * 8);
#pragma unroll
    for (int m = 0; m < 4; ++m)
#pragma unroll
      for (int n = 0; n < 4; ++n)
        acc[m][n] = mfma_bf16(af[m], bfv[n], acc[m][n]);
    __syncthreads();
  }

#pragma unroll
  for (int m = 0; m < 4; ++m) {
    int row0 = m0 + wm + m * 16 + g * 4;
#pragma unroll
    for (int n = 0; n < 4; ++n) {
      int col = n0 + wn + n * 16 + q;
      float bi = bias[col];
      int t = col >> 10;
      int h = (col >> 6) & 15;
      int d = col & 63;
#pragma unroll
      for (int r2 = 0; r2 < 4; ++r2) {
        int row = row0 + r2;
        int b = row >> 11, s = row & 2047;
        float v = acc[m][n][r2] + bi;
        size_t bh = (size_t)b * HH + h;
        if (t == 0)      Qs[(bh * SS + s) * DD + d] = f2b(v * QSCALE);
        else if (t == 1) Ks[(bh * SS + s) * DD + d] = f2b(v);
        else             Vt[(bh * DD + d) * SS + s] = f2b(v);
      }
    }
  }
}

// ---------------- causal flash attention (swapped QK^T) ----------------
// Block = 4 waves x 32 q-rows = 128-row chunk, barrier-free.
// S^T = mfma(K,Q): lane (q,g) holds S[qrow=m*16+q][kv=c*16+g*4+r2] -> row
// reduce = in-reg + 2 shuffles; P packed via v_cvt_pk_bf16_f32, 16 b32 LDS
// writes + 4 b128 reads; O^T = mfma(V^T, P).
// Grid: block b and b+256 have complementary qt and same bh (same XCD).
__global__ void __launch_bounds__(256) attn_kernel(
    const u16* __restrict__ Qg, const u16* __restrict__ Kg,
    const u16* __restrict__ Vg, u16* __restrict__ O) {
  __shared__ char lds[16384];          // per-wave 4KB P buffer (32x64 bf16, swizzled)
  int tid = threadIdx.x;
  int w = tid >> 6, lane = tid & 63;
  int g = lane >> 4, q = lane & 15;
  int b0 = blockIdx.x;
  int bh, qt;
  if (b0 < 256) { bh = b0 & 31; qt = b0 >> 5; }
  else          { bh = (b0 - 256) & 31; qt = 15 - ((b0 - 256) >> 5); }
  int qw = qt * 128 + w * 32;          // wave's first q row
  char* Pw = lds + w * 4096;
  int qsw = (q & 7) << 4;              // P swizzle for this lane's rows

  const char* Qp = (const char*)Qg + (size_t)bh * (SS * 128);
  const char* Kp = (const char*)Kg + (size_t)bh * (SS * 128);
  const char* Vp = (const char*)Vg + (size_t)bh * (SS * 128);  // [d][s]

  short8v aq[2][2];
#pragma unroll
  for (int m = 0; m < 2; ++m)
#pragma unroll
    for (int j = 0; j < 2; ++j)
      aq[m][j] = *(const short8v*)(Qp + (size_t)(qw + m * 16 + q) * 128 + j * 64 + g * 16);

  f32x4 oacc[2][4] = {};               // oacc[m][vfi]: O^T[d=vfi*16+g*4+r2][qrow=m*16+q]
  float mrun[2], lrun[2];
#pragma unroll
  for (int m = 0; m < 2; ++m) { mrun[m] = -1e30f; lrun[m] = 0.f; }

  const int nt = (qw >> 6) + 1;
  for (int t = 0; t < nt; ++t) {
    int kv0 = t << 6;
    // ---- K fragments ----
    short8v kf[4][2];
#pragma unroll
    for (int c = 0; c < 4; ++c) {
      const char* kp = Kp + (size_t)(kv0 + c * 16 + q) * 128 + g * 16;
      kf[c][0] = *(const short8v*)kp;
      kf[c][1] = *(const short8v*)(kp + 64);
    }
    // ---- S^T = K Q^T ----
    f32x4 st[2][4];
#pragma unroll
    for (int m = 0; m < 2; ++m)
#pragma unroll
      for (int c = 0; c < 4; ++c) {
        f32x4 z = {};
        z = mfma_bf16(kf[c][0], aq[m][0], z);
        z = mfma_bf16(kf[c][1], aq[m][1], z);
        st[m][c] = z;
      }
    // ---- V^T fragments (issue early; consumed after softmax) ----
    short8v vf[4][2];
#pragma unroll
    for (int v = 0; v < 4; ++v) {
      const char* vp = Vp + (size_t)(v * 16 + q) * (SS * 2) + (size_t)kv0 * 2 + g * 16;
      vf[v][0] = *(const short8v*)vp;
      vf[v][1] = *(const short8v*)(vp + 64);
    }
    // ---- causal mask (diagonal tiles only): kv = kv0+c*16+g*4+r2, row = qw+m*16+q
    if (kv0 + 63 > qw) {
#pragma unroll
      for (int m = 0; m < 2; ++m) {
        int row = qw + m * 16 + q;
#pragma unroll
        for (int c = 0; c < 4; ++c) {
          int kvb = kv0 + c * 16 + g * 4;
#pragma unroll
          for (int r2 = 0; r2 < 4; ++r2)
            if (kvb + r2 > row) st[m][c][r2] = -1e30f;
        }
      }
    }
    // ---- online softmax + P pack + PV (per m) ----
#pragma unroll
    for (int m = 0; m < 2; ++m) {
      f32x4 t01, t23;
#pragma unroll
      for (int r2 = 0; r2 < 4; ++r2) {
        t01[r2] = fmaxf(st[m][0][r2], st[m][1][r2]);
        t23[r2] = fmaxf(st[m][2][r2], st[m][3][r2]);
      }
      float mx = fmaxf(fmaxf(fmaxf(t01[0], t01[1]), fmaxf(t01[2], t01[3])),
                       fmaxf(fmaxf(t23[0], t23[1]), fmaxf(t23[2], t23[3])));
      mx = fmaxf(mx, __shfl_xor(mx, 16));
      mx = fmaxf(mx, __shfl_xor(mx, 32));
      float mnew = fmaxf(mrun[m], mx);
      float alpha = exp2f(mrun[m] - mnew);
      mrun[m] = mnew;
      f32x4 sum4 = {};
#pragma unroll
      for (int c = 0; c < 4; ++c)
#pragma unroll
        for (int r2 = 0; r2 < 4; ++r2) {
          float pv = exp2f(st[m][c][r2] - mnew);
          st[m][c][r2] = pv;
          sum4[r2] += pv;
        }
      float s = (sum4[0] + sum4[1]) + (sum4[2] + sum4[3]);
      s += __shfl_xor(s, 16);
      s += __shfl_xor(s, 32);
      lrun[m] = lrun[m] * alpha + s;
#pragma unroll
      for (int vfi = 0; vfi < 4; ++vfi)
#pragma unroll
        for (int r2 = 0; r2 < 4; ++r2) oacc[m][vfi][r2] *= alpha;
      // P -> LDS packed bf16x2 (row = m*16+q, kv-contig within lane)
      char* base = Pw + (m * 16 + q) * 128;
#pragma unroll
      for (int c = 0; c < 4; ++c) {
        unsigned p01 = cvtpk(st[m][c][0], st[m][c][1]);
        unsigned p23 = cvtpk(st[m][c][2], st[m][c][3]);
        *(unsigned*)(base + ((32 * c + 8 * g + 0) ^ qsw)) = p01;
        *(unsigned*)(base + ((32 * c + 8 * g + 4) ^ qsw)) = p23;
      }
      short8v pa0 = *(const short8v*)(base + ((g * 16) ^ qsw));
      short8v pa1 = *(const short8v*)(base + ((64 + g * 16) ^ qsw));
      // O^T += V^T P
#pragma unroll
      for (int vfi = 0; vfi < 4; ++vfi) {
        oacc[m][vfi] = mfma_bf16(vf[vfi][0], pa0, oacc[m][vfi]);
        oacc[m][vfi] = mfma_bf16(vf[vfi][1], pa1, oacc[m][vfi]);
      }
    }
  }

  int b = bh >> 4, h = bh & 15;
#pragma unroll
  for (int m = 0; m < 2; ++m) {
    float inv = 1.0f / lrun[m];
    int row = qw + m * 16 + q;
    char* base = (char*)O + (((size_t)b * SS + row) * EE + h * 64) * 2;
#pragma unroll
    for (int vfi = 0; vfi < 4; ++vfi) {
      uint2 o;
      o.x = cvtpk(oacc[m][vfi][0] * inv, oacc[m][vfi][1] * inv);
      o.y = cvtpk(oacc[m][vfi][2] * inv, oacc[m][vfi][3] * inv);
      *(uint2*)(base + (vfi * 16 + g * 4) * 2) = o;
    }
  }
}

// ---------------- output projection GEMM: out[4096,1024] = O @ Wout + bout (f32) ----------------
__global__ void __launch_bounds__(256) gemm_out_kernel(
    const u16* __restrict__ A, const u16* __restrict__ BT,
    const float* __restrict__ bias, float* __restrict__ Cout) {
  __shared__ u16 As[4096];
  __shared__ u16 Bs[4096];
  const int K = EE;
  int tid = threadIdx.x;
  int w = tid >> 6, lane = tid & 63;
  int g = lane >> 4, q = lane & 15;
  int m0 = blockIdx.y * 128, n0 = blockIdx.x * 128;
  int wm = (w >> 1) * 64, wn = (w & 1) * 64;

  f32x4 acc[4][4] = {};

  int r = tid >> 2;
  int kc = (tid & 3) * 8;
  const u16* ga = A + (size_t)(m0 + r) * K + kc;
  const u16* gb = BT + (size_t)(n0 + r) * K + kc;
  u16* lA0 = As + w * 512;
  u16* lA1 = As + 2048 + w * 512;
  u16* lB0 = Bs + w * 512;
  u16* lB1 = Bs + 2048 + w * 512;

  for (int k0 = 0; k0 < K; k0 += 32) {
    gload_lds16(ga, lA0);
    gload_lds16(ga + 64 * K, lA1);
    gload_lds16(gb, lB0);
    gload_lds16(gb + 64 * K, lB1);
    ga += 32; gb += 32;
    __syncthreads();
    short8v af[4], bfv[4];
#pragma unroll
    for (int m = 0; m < 4; ++m)
      af[m] = *(const short8v*)(As + (wm + m * 16 + q) * 32 + g * 8);
#pragma unroll
    for (int n = 0; n < 4; ++n)
      bfv[n] = *(const short8v*)(Bs + (wn + n * 16 + q) * 32 + g * 8);
#pragma unroll
    for (int m = 0; m < 4; ++m)
#pragma unroll
      for (int n = 0; n < 4; ++n)
        acc[m][n] = mfma_bf16(af[m], bfv[n], acc[m][n]);
    __syncthreads();
  }

#pragma unroll
  for (int m = 0; m < 4; ++m) {
    int row0 = m0 + wm + m * 16 + g * 4;
#pragma unroll
    for (int n = 0; n < 4; ++n) {
      int col = n0 + wn + n * 16 + q;
      float bi = bias[col];
#pragma unroll
      for (int r2 = 0; r2 < 4; ++r2) {
        int row = row0 + r2;
        Cout[(size_t)row * EE + col] = acc[m][n][r2] + bi;
      }
    }
  }
}

extern "C" void kernel_launch(void* const* d_in, const int* in_sizes, int n_in,
                              void* d_out, int out_size, void* d_ws, size_t ws_size,
                              hipStream_t stream) {
  (void)in_sizes; (void)n_in; (void)out_size; (void)ws_size;
  const float* x    = (const float*)d_in[0];
  const float* Wqkv = (const float*)d_in[1];
  const float* bqkv = (const float*)d_in[2];
  const float* Wout = (const float*)d_in[3];
  const float* bout = (const float*)d_in[4];
  float* out = (float*)d_out;

  char* p = (char*)d_ws;
  u16* xb  = (u16*)p; p += (size_t)MT * EE * 2;           // 8 MB
  u16* wqT = (u16*)p; p += (size_t)NQ * EE * 2;           // 6 MB
  u16* woT = (u16*)p; p += (size_t)EE * EE * 2;           // 2 MB
  u16* Qs  = (u16*)p; p += (size_t)BB * HH * SS * DD * 2; // 8 MB
  u16* Ks  = (u16*)p; p += (size_t)BB * HH * SS * DD * 2; // 8 MB
  u16* Vt  = (u16*)p; p += (size_t)BB * HH * DD * SS * 2; // 8 MB
  u16* Ob  = (u16*)p; p += (size_t)MT * EE * 2;           // 8 MB

  cast_kernel<<<dim3((MT * EE / 4) / 256), dim3(256), 0, stream>>>(x, xb, MT * EE);
  transpose_kernel<<<dim3(NQ / 64, EE / 64), dim3(256), 0, stream>>>(Wqkv, wqT, EE, NQ);
  transpose_kernel<<<dim3(EE / 64, EE / 64), dim3(256), 0, stream>>>(Wout, woT, EE, EE);
  gemm_qkv_kernel<<<dim3(NQ / 128, MT / 128), dim3(256), 0, stream>>>(xb, wqT, bqkv, Qs, Ks, Vt);
  attn_kernel<<<dim3(512), dim3(256), 0, stream>>>(Qs, Ks, Vt, Ob);
  gemm_out_kernel<<<dim3(EE / 128, MT / 128), dim3(256), 0, stream>>>(Ob, woT, bout, out);
}